// Round 1
// baseline (69.499 us; speedup 1.0000x reference)
//
#include <hip/hip_runtime.h>
#include <math.h>

#define A_ATOMS 48
#define RADLEN  64     // 4 species * 16 SHFR
#define ANGLEN  320    // 10 pairs * 4 SHFA * 8 SHFZ
#define FEATLEN 384
#define RCR_F 5.2f
#define RCA_F 3.5f

// cos/sin of SHFZ = k*pi/8 + pi/16, k=0..7
__device__ __constant__ float COSZ[8] = {
     0.98078528f,  0.83146961f,  0.55557023f,  0.19509032f,
    -0.19509032f, -0.55557023f, -0.83146961f, -0.98078528f};
__device__ __constant__ float SINZ[8] = {
     0.19509032f,  0.55557023f,  0.83146961f,  0.98078528f,
     0.98078528f,  0.83146961f,  0.55557023f,  0.19509032f};

__global__ __launch_bounds__(64) void aev_kernel(const int* __restrict__ species,
                                                 const float* __restrict__ coords,
                                                 float* __restrict__ out,
                                                 int N, int A) {
    const int blk = blockIdx.x;
    const int n = blk / A;
    const int i = blk - n * A;
    const int tid = threadIdx.x;

    __shared__ float sx[A_ATOMS], sy[A_ATOMS], szc[A_ATOMS];
    __shared__ int   sspec[A_ATOMS];
    __shared__ float ddx[A_ATOMS], ddy[A_ATOMS], ddz[A_ATOMS], dd[A_ATOMS];
    __shared__ float feat[FEATLEN];
    __shared__ int   nb_cnt;
    __shared__ int   nb_jj[A_ATOMS];
    __shared__ float nb_dx[A_ATOMS], nb_dy[A_ATOMS], nb_dz[A_ATOMS];
    __shared__ float nb_d[A_ATOMS], nb_fc[A_ATOMS];

    // ---- stage molecule ----
    if (tid < A) {
        const float* c = coords + ((size_t)n * A + tid) * 3;
        sx[tid]  = c[0];
        sy[tid]  = c[1];
        szc[tid] = c[2];
        sspec[tid] = species[n * A + tid];
    }
    for (int t = tid; t < FEATLEN; t += 64) feat[t] = 0.f;
    if (tid == 0) nb_cnt = 0;
    __syncthreads();

    const int  si = sspec[i];
    const bool vi = (si >= 0);
    const float xi = sx[i], yi = sy[i], zi = szc[i];

    // ---- per-j distances + RCA neighbor list ----
    if (tid < A) {
        const int j = tid;
        float dx = 0.f, dy = 0.f, dz = 0.f, d = 1e30f;
        if (vi && j != i && sspec[j] >= 0) {
            dx = xi - sx[j]; dy = yi - sy[j]; dz = zi - szc[j];
            float d2 = dx*dx + dy*dy + dz*dz;
            d = (d2 > 0.f) ? sqrtf(d2) : 1.0f;   // matches ref's where(d2>0, d2, 1)
        }
        ddx[j] = dx; ddy[j] = dy; ddz[j] = dz; dd[j] = d;
        if (d <= RCA_F) {
            int slot = atomicAdd(&nb_cnt, 1);
            nb_jj[slot] = j;
            nb_dx[slot] = dx; nb_dy[slot] = dy; nb_dz[slot] = dz;
            nb_d[slot]  = d;
            nb_fc[slot] = 0.5f * __cosf(d * (float)(M_PI / 3.5)) + 0.5f;
        }
    }
    __syncthreads();

    // ---- radial: lane owns (species s, shift f); no atomics ----
    if (tid < RADLEN) {
        const int s = tid >> 4;
        const int f = tid & 15;
        const float shfr = 0.9f + 0.26875f * (float)f;
        float acc = 0.f;
        for (int j = 0; j < A; ++j) {
            float d = dd[j];
            if (d <= RCR_F && sspec[j] == s) {
                float fc = 0.5f * __cosf(d * (float)(M_PI / 5.2)) + 0.5f;
                float e = d - shfr;
                acc += 0.25f * __expf(-16.f * e * e) * fc;
            }
        }
        feat[tid] = acc;   // disjoint from angular range; no barrier needed
    }

    // ---- angular: grid-stride over unordered neighbor pairs ----
    const int M = nb_cnt;
    const int P = (M * (M - 1)) >> 1;
    for (int p = tid; p < P; p += 64) {
        // decode flat pair index -> (a,b), a>b
        int a = (int)((1.f + sqrtf(1.f + 8.f * (float)p)) * 0.5f);
        while ((a * (a - 1)) / 2 > p) --a;
        while (((a + 1) * a) / 2 <= p) ++a;
        const int b = p - (a * (a - 1)) / 2;

        const float djx = nb_dx[a], djy = nb_dy[a], djz = nb_dz[a], dj = nb_d[a];
        const float dkx = nb_dx[b], dky = nb_dy[b], dkz = nb_dz[b], dk = nb_d[b];
        const float dotp = djx*dkx + djy*dky + djz*dkz;
        // x = cos(angle); ref: angle = acos(0.95*dot/denom).
        const float x  = 0.95f * dotp / fmaxf(dj * dk, 1e-10f);
        const float sn = sqrtf(fmaxf(0.f, 1.f - x * x));   // sin(angle) >= 0
        const float dh = 0.5f * (dj + dk);
        const int sj = sspec[nb_jj[a]];
        const int sk = sspec[nb_jj[b]];
        const int lo = (sj < sk) ? sj : sk;
        const int hi = (sj < sk) ? sk : sj;
        const int pidx = (lo * (9 - lo)) / 2 + (hi - lo);   // TRIU index, 4 species
        float* dst = &feat[RADLEN + pidx * 32];
        const float base = 2.f * nb_fc[a] * nb_fc[b];
        #pragma unroll
        for (int aa = 0; aa < 4; ++aa) {
            float e  = dh - (0.9f + 0.65f * (float)aa);
            float f2 = base * __expf(-8.f * e * e);
            #pragma unroll
            for (int zz = 0; zz < 8; ++zz) {
                // cos(angle - shfz) = x*cos(shfz) + sin(angle)*sin(shfz)
                float c = x * COSZ[zz] + sn * SINZ[zz];
                float t = 0.5f * (1.f + c);
                float t2 = t * t, t4 = t2 * t2, t8 = t4 * t4, t16 = t8 * t8;
                atomicAdd(&dst[aa * 8 + zz], f2 * (t16 * t16));  // t^32
            }
        }
    }
    __syncthreads();

    // ---- write (n,i,384) ----
    float* o = out + (size_t)blk * FEATLEN;
    for (int t = tid; t < FEATLEN; t += 64) o[t] = feat[t];
}

extern "C" void kernel_launch(void* const* d_in, const int* in_sizes, int n_in,
                              void* d_out, int out_size, void* d_ws, size_t ws_size,
                              hipStream_t stream) {
    const int*   species = (const int*)d_in[0];
    const float* coords  = (const float*)d_in[1];
    float*       out     = (float*)d_out;
    const int NA = in_sizes[0];        // N*A = 1536
    const int A  = A_ATOMS;
    const int N  = NA / A;
    aev_kernel<<<dim3(NA), dim3(64), 0, stream>>>(species, coords, out, N, A);
}